// Round 1
// baseline (320.196 us; speedup 1.0000x reference)
//
#include <hip/hip_runtime.h>
#include <math.h>

#define NEG_SLOPE 0.2f

__device__ __forceinline__ float dot4f(float4 a, float4 b) {
    return a.x * b.x + a.y * b.y + a.z * b.z + a.w * b.w;
}

// ---------------------------------------------------------------------------
// Kernel 1: y[n] = |feat[n]·p| / ||p||, gate[n] = 2*sigmoid(y[n])
// One wave (64 lanes) per node; lane i holds float4 = feat[n, 4i..4i+3].
// ---------------------------------------------------------------------------
__global__ __launch_bounds__(256) void k_score(const float4* __restrict__ feat4,
                                               const float4* __restrict__ p4,
                                               float* __restrict__ y,
                                               float* __restrict__ gate,
                                               int N) {
    const int lane = threadIdx.x & 63;
    const int n = blockIdx.x * 4 + (threadIdx.x >> 6);
    if (n >= N) return;
    float4 f = feat4[(size_t)n * 64 + lane];
    float4 p = p4[lane];
    float dp = dot4f(f, p);
    float pp = dot4f(p, p);
#pragma unroll
    for (int off = 32; off; off >>= 1) {
        dp += __shfl_xor(dp, off, 64);
        pp += __shfl_xor(pp, off, 64);
    }
    if (lane == 0) {
        float yv = fabsf(dp) / sqrtf(pp);
        y[n] = yv;
        gate[n] = 2.0f / (1.0f + expf(-yv));
    }
}

// ---------------------------------------------------------------------------
// Kernel 2: ft = (gate * feat) @ W   — fp32 register-tiled GEMM (no fp32 MFMA
// on CDNA4, vector ALU). Block = 256 threads (16x16), 64-row block, 64-col
// tiles (ct=0..3), K-tiles of 64 (kt=0..3). Each thread computes 4 rows x 4
// cols per ct = 64 outputs total. As padded to stride 68 -> a-frag b128 reads
// are 2-way (free); Ws reads 2-way (free).
// ---------------------------------------------------------------------------
__global__ __launch_bounds__(256) void k_gemm(const float4* __restrict__ feat4,
                                              const float4* __restrict__ W4,
                                              const float* __restrict__ gate,
                                              float4* __restrict__ ft4,
                                              int N) {
    __shared__ float As[64][68];   // [row][f]   (stride 68 breaks conflicts)
    __shared__ float Ws[64][64];   // [f][col]
    const int t = threadIdx.x;
    const int tx = t & 15, ty = t >> 4;
    const int tx4 = tx * 4, ty4 = ty * 4;
    const int n0 = blockIdx.x * 64;

    float4 acc[4][4];  // [ct][r] -> 4 col components
#pragma unroll
    for (int ct = 0; ct < 4; ++ct)
#pragma unroll
        for (int r = 0; r < 4; ++r) acc[ct][r] = make_float4(0.f, 0.f, 0.f, 0.f);

    for (int kt = 0; kt < 4; ++kt) {
        __syncthreads();  // previous As/Ws consumers done
        // stage A (gated): As[r][c] = gate[n0+r] * feat[n0+r][kt*64+c]
#pragma unroll
        for (int i = 0; i < 4; ++i) {
            int idx = i * 256 + t;
            int r = idx >> 4, c = idx & 15;
            int row = n0 + r;
            float g = 0.f;
            float4 v = make_float4(0.f, 0.f, 0.f, 0.f);
            if (row < N) {
                g = gate[row];
                v = feat4[(size_t)row * 64 + kt * 16 + c];
            }
            float4 gv = make_float4(g * v.x, g * v.y, g * v.z, g * v.w);
            *(float4*)&As[r][c * 4] = gv;
        }
#pragma unroll
        for (int ct = 0; ct < 4; ++ct) {
            if (ct) __syncthreads();  // done reading Ws(ct-1)
            // stage W tile: Ws[f][c] = W[kt*64+f][ct*64+c]
#pragma unroll
            for (int i = 0; i < 4; ++i) {
                int idx = i * 256 + t;
                int f = idx >> 4, c4 = idx & 15;
                float4 w = W4[(size_t)(kt * 64 + f) * 64 + ct * 16 + c4];
                *(float4*)&Ws[f][c4 * 4] = w;
            }
            __syncthreads();  // As + Ws visible
            for (int f0 = 0; f0 < 64; f0 += 4) {
                float4 a0 = *(const float4*)&As[ty4 + 0][f0];
                float4 a1 = *(const float4*)&As[ty4 + 1][f0];
                float4 a2 = *(const float4*)&As[ty4 + 2][f0];
                float4 a3 = *(const float4*)&As[ty4 + 3][f0];
                float4 w0 = *(const float4*)&Ws[f0 + 0][tx4];
                float4 w1 = *(const float4*)&Ws[f0 + 1][tx4];
                float4 w2 = *(const float4*)&Ws[f0 + 2][tx4];
                float4 w3 = *(const float4*)&Ws[f0 + 3][tx4];
#define MMA4(ACC, A)                                                        \
    ACC.x += A.x * w0.x + A.y * w1.x + A.z * w2.x + A.w * w3.x;             \
    ACC.y += A.x * w0.y + A.y * w1.y + A.z * w2.y + A.w * w3.y;             \
    ACC.z += A.x * w0.z + A.y * w1.z + A.z * w2.z + A.w * w3.z;             \
    ACC.w += A.x * w0.w + A.y * w1.w + A.z * w2.w + A.w * w3.w;
                MMA4(acc[ct][0], a0)
                MMA4(acc[ct][1], a1)
                MMA4(acc[ct][2], a2)
                MMA4(acc[ct][3], a3)
#undef MMA4
            }
        }
    }
    // write ft
#pragma unroll
    for (int ct = 0; ct < 4; ++ct)
#pragma unroll
        for (int r = 0; r < 4; ++r) {
            int row = n0 + ty4 + r;
            if (row < N) ft4[(size_t)row * 64 + ct * 16 + tx] = acc[ct][r];
        }
}

// ---------------------------------------------------------------------------
// Kernel 3: per node — top-8 neighbors by y[src] (tie-break: lower slot index,
// matching jax.lax.top_k), gather ft rows, compute el/er from gathered rows,
// leaky-relu, softmax over k, weighted sum, elu.
// One wave per node. Lane covers float4 index -> h = lane>>3, o = (lane&7)*4+j.
// ---------------------------------------------------------------------------
__global__ __launch_bounds__(256) void k_aggr(const int* __restrict__ nbr,
                                              const float* __restrict__ y,
                                              const float4* __restrict__ ft4,
                                              const float4* __restrict__ al4,
                                              const float4* __restrict__ ar4,
                                              float4* __restrict__ out4,
                                              int N) {
    const int lane = threadIdx.x & 63;
    const int n = blockIdx.x * 4 + (threadIdx.x >> 6);
    if (n >= N) return;

    const int s = nbr[(size_t)n * 64 + lane];
    const float yv = y[s];

    // --- top-8 selection: (value desc, slot-index asc) total order ---
    float vv = yv;
    int sel[8];
#pragma unroll
    for (int k = 0; k < 8; ++k) {
        float bv = vv;
        int bd = lane;
#pragma unroll
        for (int off = 32; off; off >>= 1) {
            float ov = __shfl_xor(bv, off, 64);
            int od = __shfl_xor(bd, off, 64);
            if (ov > bv || (ov == bv && od < bd)) { bv = ov; bd = od; }
        }
        sel[k] = bd;                       // all lanes converge
        if (lane == bd) vv = -INFINITY;    // remove winner
    }
    int srck[8];
#pragma unroll
    for (int k = 0; k < 8; ++k) srck[k] = __shfl(s, sel[k], 64);

    // --- gather ft rows (own + 8 sources), 1 float4 per lane per row ---
    float4 ftn = ft4[(size_t)n * 64 + lane];
    float4 ftk[8];
#pragma unroll
    for (int k = 0; k < 8; ++k) ftk[k] = ft4[(size_t)srck[k] * 64 + lane];

    const float4 al = al4[lane];
    const float4 ar = ar4[lane];

    // er[n,h]: dot over o within h-group (8 lanes)
    float er = dot4f(ftn, ar);
#pragma unroll
    for (int off = 1; off < 8; off <<= 1) er += __shfl_xor(er, off, 64);

    // e[k,h] = leaky(el[src_k,h] + er[n,h])
    float e[8];
#pragma unroll
    for (int k = 0; k < 8; ++k) {
        float el = dot4f(ftk[k], al);
#pragma unroll
        for (int off = 1; off < 8; off <<= 1) el += __shfl_xor(el, off, 64);
        float ev = el + er;
        e[k] = ev > 0.f ? ev : NEG_SLOPE * ev;
    }

    // softmax over k (redundant across the 8 lanes of each h-group; fine)
    float m = e[0];
#pragma unroll
    for (int k = 1; k < 8; ++k) m = fmaxf(m, e[k]);
    float sum = 0.f;
#pragma unroll
    for (int k = 0; k < 8; ++k) {
        e[k] = expf(e[k] - m);
        sum += e[k];
    }
    const float inv = 1.0f / sum;

    float4 acc = make_float4(0.f, 0.f, 0.f, 0.f);
#pragma unroll
    for (int k = 0; k < 8; ++k) {
        float a = e[k] * inv;
        acc.x += a * ftk[k].x;
        acc.y += a * ftk[k].y;
        acc.z += a * ftk[k].z;
        acc.w += a * ftk[k].w;
    }
    // elu
    acc.x = acc.x > 0.f ? acc.x : expf(acc.x) - 1.f;
    acc.y = acc.y > 0.f ? acc.y : expf(acc.y) - 1.f;
    acc.z = acc.z > 0.f ? acc.z : expf(acc.z) - 1.f;
    acc.w = acc.w > 0.f ? acc.w : expf(acc.w) - 1.f;
    out4[(size_t)n * 64 + lane] = acc;
}

// ---------------------------------------------------------------------------
extern "C" void kernel_launch(void* const* d_in, const int* in_sizes, int n_in,
                              void* d_out, int out_size, void* d_ws, size_t ws_size,
                              hipStream_t stream) {
    const float* feat = (const float*)d_in[0];   // [N,256] fp32
    const int* nbr    = (const int*)d_in[1];     // [N,64] int32
    const float* p    = (const float*)d_in[2];   // [1,256]
    const float* W    = (const float*)d_in[3];   // [256,256]
    const float* al   = (const float*)d_in[4];   // [1,8,32]
    const float* ar   = (const float*)d_in[5];   // [1,8,32]
    float* out = (float*)d_out;                  // [N,8,32] fp32

    const int N = in_sizes[0] / 256;

    // workspace: y [N] f32 | gate [N] f32 | ft [N*256] f32  (~51.6 MB)
    float* y    = (float*)d_ws;
    float* gate = y + N;
    float* ft   = gate + N;   // byte offset 8N = 400000 -> 16B aligned

    const int nb4 = (N + 3) / 4;
    k_score<<<nb4, 256, 0, stream>>>((const float4*)feat, (const float4*)p, y, gate, N);
    k_gemm<<<(N + 63) / 64, 256, 0, stream>>>((const float4*)feat, (const float4*)W,
                                              gate, (float4*)ft, N);
    k_aggr<<<nb4, 256, 0, stream>>>(nbr, y, (const float4*)ft,
                                    (const float4*)al, (const float4*)ar,
                                    (float4*)out, N);
}

// Round 2
// 227.263 us; speedup vs baseline: 1.4089x; 1.4089x over previous
//
#include <hip/hip_runtime.h>
#include <math.h>

#define NEG_SLOPE 0.2f

typedef _Float16 half8 __attribute__((ext_vector_type(8)));
typedef float floatx4 __attribute__((ext_vector_type(4)));

__device__ __forceinline__ float dot4f(float4 a, float4 b) {
    return a.x * b.x + a.y * b.y + a.z * b.z + a.w * b.w;
}

static __device__ __forceinline__ unsigned short f2h(float x) {
    _Float16 h = (_Float16)x;               // RNE
    return __builtin_bit_cast(unsigned short, h);
}
static __device__ __forceinline__ float h2f(unsigned short u) {
    _Float16 h = __builtin_bit_cast(_Float16, u);
    return (float)h;
}

// ---------------------------------------------------------------------------
// Kernel 1: y[n] = |feat[n].p| / ||p||; also writes Ah = (2*sigmoid(y)) * feat
// as fp16 (the GEMM's pre-gated A matrix). One wave per node.
// ---------------------------------------------------------------------------
__global__ __launch_bounds__(256) void k_score(const float4* __restrict__ feat4,
                                               const float4* __restrict__ p4,
                                               float* __restrict__ y,
                                               ushort4* __restrict__ Ah4,
                                               int N) {
    const int lane = threadIdx.x & 63;
    const int n = blockIdx.x * 4 + (threadIdx.x >> 6);
    if (n >= N) return;
    float4 f = feat4[(size_t)n * 64 + lane];
    float4 p = p4[lane];
    float dp = dot4f(f, p);
    float pp = dot4f(p, p);
#pragma unroll
    for (int off = 32; off; off >>= 1) {
        dp += __shfl_xor(dp, off, 64);
        pp += __shfl_xor(pp, off, 64);
    }
    float yv = fabsf(dp) / sqrtf(pp);       // same in all lanes
    if (lane == 0) y[n] = yv;
    float g = 2.0f / (1.0f + expf(-yv));
    ushort4 u;
    u.x = f2h(g * f.x);
    u.y = f2h(g * f.y);
    u.z = f2h(g * f.z);
    u.w = f2h(g * f.w);
    Ah4[(size_t)n * 64 + lane] = u;         // 8B/lane, coalesced
}

// ---------------------------------------------------------------------------
// Kernel 1b: Wt[c][k] = fp16(W[k][c])  (transposed so B-fragments are
// k-contiguous 16B loads). 128 KB total, L2-resident for the GEMM.
// ---------------------------------------------------------------------------
__global__ void k_prepw(const float* __restrict__ W, unsigned short* __restrict__ Wt) {
    const int c = blockIdx.x;       // 256
    const int k = threadIdx.x;      // 256
    Wt[(size_t)c * 256 + k] = f2h(W[(size_t)k * 256 + c]);
}

// ---------------------------------------------------------------------------
// Kernel 2: ft = A @ W via v_mfma_f32_16x16x32_f16, fp32 accumulate, fp16 out.
// Barrier-free: A/B fragments loaded straight from global (no LDS), so the
// compiler can pipeline loads across the whole K loop. Block = 4 waves;
// block tile 32 rows x 256 cols (wave w owns cols w*64..w*64+63 = 2x4 MFMA
// tiles of 16x16). grid = ceil(N/32) = 1563 blocks (~6/CU).
// A-frag layout: A[m = lane&15][k = (lane>>4)*8 + j]; B: B[k][n = lane&15].
// C/D: col = lane&15, row = (lane>>4)*4 + reg  (learn_hip m89/m91 verified).
// ---------------------------------------------------------------------------
__global__ __launch_bounds__(256) void k_gemm_mfma(const unsigned short* __restrict__ Ah,
                                                   const unsigned short* __restrict__ Wt,
                                                   unsigned short* __restrict__ fth,
                                                   int N) {
    const int lane = threadIdx.x & 63;
    const int w = threadIdx.x >> 6;           // wave id 0..3
    const int l16 = lane & 15, quad = lane >> 4;
    const int n0 = blockIdx.x * 32;
    const int c0 = w * 64;

    floatx4 acc[2][4];
#pragma unroll
    for (int mt = 0; mt < 2; ++mt)
#pragma unroll
        for (int ct = 0; ct < 4; ++ct) acc[mt][ct] = (floatx4){0.f, 0.f, 0.f, 0.f};

    const unsigned short* aptr[2];
#pragma unroll
    for (int mt = 0; mt < 2; ++mt) {
        int r = n0 + mt * 16 + l16;
        if (r >= N) r = N - 1;                // clamp: safe read, store masked
        aptr[mt] = Ah + (size_t)r * 256 + quad * 8;
    }
    const unsigned short* bptr[4];
#pragma unroll
    for (int ct = 0; ct < 4; ++ct) {
        int c = c0 + ct * 16 + l16;
        bptr[ct] = Wt + (size_t)c * 256 + quad * 8;
    }

    for (int ks = 0; ks < 256; ks += 32) {
        half8 a[2], b[4];
#pragma unroll
        for (int mt = 0; mt < 2; ++mt) a[mt] = *(const half8*)(aptr[mt] + ks);
#pragma unroll
        for (int ct = 0; ct < 4; ++ct) b[ct] = *(const half8*)(bptr[ct] + ks);
#pragma unroll
        for (int mt = 0; mt < 2; ++mt)
#pragma unroll
            for (int ct = 0; ct < 4; ++ct)
                acc[mt][ct] = __builtin_amdgcn_mfma_f32_16x16x32_f16(
                    a[mt], b[ct], acc[mt][ct], 0, 0, 0);
    }

#pragma unroll
    for (int mt = 0; mt < 2; ++mt)
#pragma unroll
        for (int ct = 0; ct < 4; ++ct)
#pragma unroll
            for (int i = 0; i < 4; ++i) {
                int row = n0 + mt * 16 + quad * 4 + i;
                if (row < N)
                    fth[(size_t)row * 256 + c0 + ct * 16 + l16] = f2h(acc[mt][ct][i]);
            }
}

// ---------------------------------------------------------------------------
// Kernel 3: per node — top-8 neighbors by y[src] (tie: lower slot index,
// matching jax.lax.top_k), gather fp16 ft rows, el/er from gathered rows,
// leaky-relu, softmax over k, weighted sum, elu. One wave per node; lane
// holds elements 4*lane..4*lane+3 (h = lane>>3).
// ---------------------------------------------------------------------------
__global__ __launch_bounds__(256) void k_aggr(const int* __restrict__ nbr,
                                              const float* __restrict__ y,
                                              const uint2* __restrict__ fth2,
                                              const float4* __restrict__ al4,
                                              const float4* __restrict__ ar4,
                                              float4* __restrict__ out4,
                                              int N) {
    const int lane = threadIdx.x & 63;
    const int n = blockIdx.x * 4 + (threadIdx.x >> 6);
    if (n >= N) return;

    const int s = nbr[(size_t)n * 64 + lane];
    const float yv = y[s];

    // --- top-8: (value desc, slot-index asc) total order ---
    float vv = yv;
    int sel[8];
#pragma unroll
    for (int k = 0; k < 8; ++k) {
        float bv = vv;
        int bd = lane;
#pragma unroll
        for (int off = 32; off; off >>= 1) {
            float ov = __shfl_xor(bv, off, 64);
            int od = __shfl_xor(bd, off, 64);
            if (ov > bv || (ov == bv && od < bd)) { bv = ov; bd = od; }
        }
        sel[k] = bd;
        if (lane == bd) vv = -INFINITY;
    }
    int srck[8];
#pragma unroll
    for (int k = 0; k < 8; ++k) srck[k] = __shfl(s, sel[k], 64);

    // --- gather fp16 rows: 8B (4 halves) per lane per row, coalesced ---
    float4 ftn, ftk[8];
    {
        uint2 v = fth2[(size_t)n * 64 + lane];
        ftn.x = h2f((unsigned short)(v.x & 0xffff));
        ftn.y = h2f((unsigned short)(v.x >> 16));
        ftn.z = h2f((unsigned short)(v.y & 0xffff));
        ftn.w = h2f((unsigned short)(v.y >> 16));
    }
#pragma unroll
    for (int k = 0; k < 8; ++k) {
        uint2 v = fth2[(size_t)srck[k] * 64 + lane];
        ftk[k].x = h2f((unsigned short)(v.x & 0xffff));
        ftk[k].y = h2f((unsigned short)(v.x >> 16));
        ftk[k].z = h2f((unsigned short)(v.y & 0xffff));
        ftk[k].w = h2f((unsigned short)(v.y >> 16));
    }

    const float4 al = al4[lane];
    const float4 ar = ar4[lane];

    float er = dot4f(ftn, ar);
#pragma unroll
    for (int off = 1; off < 8; off <<= 1) er += __shfl_xor(er, off, 64);

    float e[8];
#pragma unroll
    for (int k = 0; k < 8; ++k) {
        float el = dot4f(ftk[k], al);
#pragma unroll
        for (int off = 1; off < 8; off <<= 1) el += __shfl_xor(el, off, 64);
        float ev = el + er;
        e[k] = ev > 0.f ? ev : NEG_SLOPE * ev;
    }

    float m = e[0];
#pragma unroll
    for (int k = 1; k < 8; ++k) m = fmaxf(m, e[k]);
    float sum = 0.f;
#pragma unroll
    for (int k = 0; k < 8; ++k) {
        e[k] = expf(e[k] - m);
        sum += e[k];
    }
    const float inv = 1.0f / sum;

    float4 acc = make_float4(0.f, 0.f, 0.f, 0.f);
#pragma unroll
    for (int k = 0; k < 8; ++k) {
        float a = e[k] * inv;
        acc.x += a * ftk[k].x;
        acc.y += a * ftk[k].y;
        acc.z += a * ftk[k].z;
        acc.w += a * ftk[k].w;
    }
    acc.x = acc.x > 0.f ? acc.x : expf(acc.x) - 1.f;
    acc.y = acc.y > 0.f ? acc.y : expf(acc.y) - 1.f;
    acc.z = acc.z > 0.f ? acc.z : expf(acc.z) - 1.f;
    acc.w = acc.w > 0.f ? acc.w : expf(acc.w) - 1.f;
    out4[(size_t)n * 64 + lane] = acc;
}

// ---------------------------------------------------------------------------
extern "C" void kernel_launch(void* const* d_in, const int* in_sizes, int n_in,
                              void* d_out, int out_size, void* d_ws, size_t ws_size,
                              hipStream_t stream) {
    const float* feat = (const float*)d_in[0];   // [N,256] fp32
    const int* nbr    = (const int*)d_in[1];     // [N,64] int32
    const float* p    = (const float*)d_in[2];   // [1,256]
    const float* W    = (const float*)d_in[3];   // [256,256]
    const float* al   = (const float*)d_in[4];   // [1,8,32]
    const float* ar   = (const float*)d_in[5];   // [1,8,32]
    float* out = (float*)d_out;                  // [N,8,32] fp32

    const int N = in_sizes[0] / 256;

    // workspace: y[N] f32 | Ah[N*256] fp16 | Wt[256*256] fp16 | ft[N*256] fp16
    // = 200000 + 25.6e6 + 131072 + 25.6e6 = 51.53 MB (< 51.6 MB proven safe)
    float* y = (float*)d_ws;
    unsigned short* Ah  = (unsigned short*)(y + N);
    unsigned short* Wt  = Ah + (size_t)N * 256;
    unsigned short* fth = Wt + 256 * 256;

    const int nb4 = (N + 3) / 4;
    k_score<<<nb4, 256, 0, stream>>>((const float4*)feat, (const float4*)p,
                                     y, (ushort4*)Ah, N);
    k_prepw<<<256, 256, 0, stream>>>(W, Wt);
    k_gemm_mfma<<<(N + 31) / 32, 256, 0, stream>>>(Ah, Wt, fth, N);
    k_aggr<<<nb4, 256, 0, stream>>>(nbr, y, (const uint2*)fth,
                                    (const float4*)al, (const float4*)ar,
                                    (float4*)out, N);
}

// Round 3
// 176.574 us; speedup vs baseline: 1.8134x; 1.2871x over previous
//
#include <hip/hip_runtime.h>
#include <math.h>

#define NEG_SLOPE 0.2f

typedef _Float16 half8 __attribute__((ext_vector_type(8)));
typedef float floatx4 __attribute__((ext_vector_type(4)));

__device__ __forceinline__ float dot4f(float4 a, float4 b) {
    return a.x * b.x + a.y * b.y + a.z * b.z + a.w * b.w;
}

static __device__ __forceinline__ unsigned short f2h(float x) {
    _Float16 h = (_Float16)x;               // RNE
    return __builtin_bit_cast(unsigned short, h);
}
static __device__ __forceinline__ float h2f(unsigned short u) {
    _Float16 h = __builtin_bit_cast(_Float16, u);
    return (float)h;
}

// ---------------------------------------------------------------------------
// Kernel 0: permute W -> Wtp fp16 in MFMA-B-fragment order:
// Wtp[cp][kc][cm][j] = fp16(W[kc*8+j][cp*16+cm]),  cp=col/16, kc=k/8.
// One-time 128 KB, L2-resident for the fused GEMM.
// ---------------------------------------------------------------------------
__global__ void k_prepw(const float* __restrict__ W, unsigned short* __restrict__ Wtp) {
    const int c = blockIdx.x;       // 256 cols
    const int k = threadIdx.x;      // 256 ks
    float v = W[(size_t)k * 256 + c];
    Wtp[(size_t)(c >> 4) * 4096 + (k >> 3) * 128 + (c & 15) * 8 + (k & 7)] = f2h(v);
}

// ---------------------------------------------------------------------------
// Kernel 1 (fused score + GEMM): block = 256 thr = 4 waves = 16 nodes = one
// MFMA A-panel. Phase A: per node compute y = |feat.p|/||p||, gate, write
// gated fp16 row into LDS panel (stride 264 halves -> 16B-aligned rows,
// bank-capacity-floor access patterns). Phase B: 16x256 @ 256x256 matmul,
// A-frag = ds_read_b128 from LDS (A[m=l16][k=quad*8+j]), B-frag = coalesced
// 16B global loads from Wtp. C/D layout: col=lane&15, row=quad*4+reg.
// ---------------------------------------------------------------------------
__global__ __launch_bounds__(256) void k_fused(const float4* __restrict__ feat4,
                                               const float4* __restrict__ p4,
                                               const unsigned short* __restrict__ Wtp,
                                               float* __restrict__ y,
                                               unsigned short* __restrict__ fth,
                                               int N) {
    __shared__ unsigned short As[16][264];   // 16 rows x 256 halves, padded
    const int lane = threadIdx.x & 63;
    const int w = threadIdx.x >> 6;          // wave 0..3
    const int l16 = lane & 15, quad = lane >> 4;
    const int nb = blockIdx.x * 16;

    const float4 p = p4[lane];
    float pp = dot4f(p, p);
#pragma unroll
    for (int off = 32; off; off >>= 1) pp += __shfl_xor(pp, off, 64);
    const float rnorm = 1.0f / sqrtf(pp);

    // ---- phase A: 4 nodes per wave ----
#pragma unroll
    for (int j = 0; j < 4; ++j) {
        const int m = w * 4 + j;
        int n = nb + m;
        const bool valid = n < N;
        if (!valid) n = N - 1;
        float4 f = feat4[(size_t)n * 64 + lane];
        float dp = dot4f(f, p);
#pragma unroll
        for (int off = 32; off; off >>= 1) dp += __shfl_xor(dp, off, 64);
        float yv = fabsf(dp) * rnorm;
        if (lane == 0 && valid) y[n] = yv;
        float g = 2.0f / (1.0f + expf(-yv));
        ushort4 u;
        u.x = f2h(g * f.x);
        u.y = f2h(g * f.y);
        u.z = f2h(g * f.z);
        u.w = f2h(g * f.w);
        *(ushort4*)&As[m][lane * 4] = u;
    }
    __syncthreads();

    // ---- phase B: matmul. wave w owns cols w*64 .. w*64+63 (col-panels 4w..4w+3)
    floatx4 acc[4];
#pragma unroll
    for (int ct = 0; ct < 4; ++ct) acc[ct] = (floatx4){0.f, 0.f, 0.f, 0.f};

    const unsigned short* bbase = Wtp + (size_t)(w * 4) * 4096 + quad * 128 + l16 * 8;

    for (int ks = 0; ks < 256; ks += 32) {
        half8 a = *(const half8*)&As[l16][ks + quad * 8];
        const unsigned short* bk = bbase + (ks >> 3) * 128;
        half8 b0 = *(const half8*)(bk);
        half8 b1 = *(const half8*)(bk + 4096);
        half8 b2 = *(const half8*)(bk + 8192);
        half8 b3 = *(const half8*)(bk + 12288);
        acc[0] = __builtin_amdgcn_mfma_f32_16x16x32_f16(a, b0, acc[0], 0, 0, 0);
        acc[1] = __builtin_amdgcn_mfma_f32_16x16x32_f16(a, b1, acc[1], 0, 0, 0);
        acc[2] = __builtin_amdgcn_mfma_f32_16x16x32_f16(a, b2, acc[2], 0, 0, 0);
        acc[3] = __builtin_amdgcn_mfma_f32_16x16x32_f16(a, b3, acc[3], 0, 0, 0);
    }

    // ---- epilogue: fth row-major [row][256] fp16 ----
#pragma unroll
    for (int ct = 0; ct < 4; ++ct)
#pragma unroll
        for (int i = 0; i < 4; ++i) {
            int row = nb + quad * 4 + i;
            if (row < N)
                fth[(size_t)row * 256 + w * 64 + ct * 16 + l16] = f2h(acc[ct][i]);
        }
}

// ---------------------------------------------------------------------------
// Kernel 2: per node — top-8 neighbors by y[src] via ballot radix-select
// (exact 8th-largest fp32-bit value; tie -> lowest slot, matching jax),
// gather fp16 ft rows, el/er from gathered rows, leaky-relu, softmax over k,
// weighted sum, elu. One wave per node; lane holds o-chunk 4*lane..4*lane+3.
// ---------------------------------------------------------------------------
__global__ __launch_bounds__(256) void k_aggr(const int* __restrict__ nbr,
                                              const float* __restrict__ y,
                                              const uint2* __restrict__ fth2,
                                              const float4* __restrict__ al4,
                                              const float4* __restrict__ ar4,
                                              float4* __restrict__ out4,
                                              int N) {
    const int lane = threadIdx.x & 63;
    const int n = blockIdx.x * 4 + (threadIdx.x >> 6);
    if (n >= N) return;

    const int s = nbr[(size_t)n * 64 + lane];
    const unsigned int key = __float_as_uint(y[s]);   // y >= 0 -> order-monotone

    // --- radix-select the exact 8th-largest key (MSB-first binary search) ---
    unsigned int t = 0u;
#pragma unroll
    for (int b = 31; b >= 0; --b) {
        unsigned int cand = t | (1u << b);
        unsigned long long m = __ballot(key >= cand);
        if (__popcll(m) >= 8) t = cand;   // feasibility monotone in t
    }
    const unsigned long long gtmask = __ballot(key > t);
    const int ngt = __popcll(gtmask);                       // <= 7
    const unsigned long long eqmask = __ballot(key == t);
    const unsigned long long below = (1ull << lane) - 1ull; // lane <= 63: defined
    const int eqrank = __popcll(eqmask & below);
    const bool in8 = (key > t) | ((key == t) & (eqrank < 8 - ngt));
    unsigned long long selmask = __ballot(in8);             // exactly 8 bits

    int srck[8];
#pragma unroll
    for (int k = 0; k < 8; ++k) {
        int l = __ffsll((long long)selmask) - 1;            // lowest set lane
        srck[k] = __shfl(s, l, 64);
        selmask &= selmask - 1ull;
    }

    // --- gather fp16 rows: 8B per lane per row, coalesced within wave ---
    float4 ftn, ftk[8];
    {
        uint2 v = fth2[(size_t)n * 64 + lane];
        ftn.x = h2f((unsigned short)(v.x & 0xffff));
        ftn.y = h2f((unsigned short)(v.x >> 16));
        ftn.z = h2f((unsigned short)(v.y & 0xffff));
        ftn.w = h2f((unsigned short)(v.y >> 16));
    }
#pragma unroll
    for (int k = 0; k < 8; ++k) {
        uint2 v = fth2[(size_t)srck[k] * 64 + lane];
        ftk[k].x = h2f((unsigned short)(v.x & 0xffff));
        ftk[k].y = h2f((unsigned short)(v.x >> 16));
        ftk[k].z = h2f((unsigned short)(v.y & 0xffff));
        ftk[k].w = h2f((unsigned short)(v.y >> 16));
    }

    const float4 al = al4[lane];
    const float4 ar = ar4[lane];

    float er = dot4f(ftn, ar);
#pragma unroll
    for (int off = 1; off < 8; off <<= 1) er += __shfl_xor(er, off, 64);

    float e[8];
#pragma unroll
    for (int k = 0; k < 8; ++k) {
        float el = dot4f(ftk[k], al);
#pragma unroll
        for (int off = 1; off < 8; off <<= 1) el += __shfl_xor(el, off, 64);
        float ev = el + er;
        e[k] = ev > 0.f ? ev : NEG_SLOPE * ev;
    }

    float m = e[0];
#pragma unroll
    for (int k = 1; k < 8; ++k) m = fmaxf(m, e[k]);
    float sum = 0.f;
#pragma unroll
    for (int k = 0; k < 8; ++k) {
        e[k] = expf(e[k] - m);
        sum += e[k];
    }
    const float inv = 1.0f / sum;

    float4 acc = make_float4(0.f, 0.f, 0.f, 0.f);
#pragma unroll
    for (int k = 0; k < 8; ++k) {
        float a = e[k] * inv;
        acc.x += a * ftk[k].x;
        acc.y += a * ftk[k].y;
        acc.z += a * ftk[k].z;
        acc.w += a * ftk[k].w;
    }
    acc.x = acc.x > 0.f ? acc.x : expf(acc.x) - 1.f;
    acc.y = acc.y > 0.f ? acc.y : expf(acc.y) - 1.f;
    acc.z = acc.z > 0.f ? acc.z : expf(acc.z) - 1.f;
    acc.w = acc.w > 0.f ? acc.w : expf(acc.w) - 1.f;
    out4[(size_t)n * 64 + lane] = acc;
}

// ---------------------------------------------------------------------------
extern "C" void kernel_launch(void* const* d_in, const int* in_sizes, int n_in,
                              void* d_out, int out_size, void* d_ws, size_t ws_size,
                              hipStream_t stream) {
    const float* feat = (const float*)d_in[0];   // [N,256] fp32
    const int* nbr    = (const int*)d_in[1];     // [N,64] int32
    const float* p    = (const float*)d_in[2];   // [1,256]
    const float* W    = (const float*)d_in[3];   // [256,256]
    const float* al   = (const float*)d_in[4];   // [1,8,32]
    const float* ar   = (const float*)d_in[5];   // [1,8,32]
    float* out = (float*)d_out;                  // [N,8,32] fp32

    const int N = in_sizes[0] / 256;

    // workspace: y[N] f32 | Wtp[256*256] fp16 | fth[N*256] fp16  (~25.9 MB)
    float* y = (float*)d_ws;
    unsigned short* Wtp = (unsigned short*)(y + N);
    unsigned short* fth = Wtp + 256 * 256;

    k_prepw<<<256, 256, 0, stream>>>(W, Wtp);
    k_fused<<<(N + 15) / 16, 256, 0, stream>>>((const float4*)feat, (const float4*)p,
                                               Wtp, y, fth, N);
    k_aggr<<<(N + 3) / 4, 256, 0, stream>>>(nbr, y, (const uint2*)fth,
                                            (const float4*)al, (const float4*)ar,
                                            (float4*)out, N);
}